// Round 9
// baseline (53.472 us; speedup 1.0000x reference)
//
#include <hip/hip_runtime.h>
#include <hip/hip_bf16.h>

typedef __attribute__((ext_vector_type(8))) short short8;
typedef __attribute__((ext_vector_type(4))) float f32x4;
typedef __attribute__((ext_vector_type(2))) float f32x2;

#define NROWS   262144
#define ODIM    64
#define NBLOCKS 256
#define TPB     1024          // 16 waves; 98 KB LDS -> 1 block/CU -> 4 waves/SIMD
#define NFRAG   (24*4*64)     // 6144 fragments = 98304 B
#define INV2PI  0.15915494309189535f

__device__ __forceinline__ float cos2pi(float f){ float r; asm("v_cos_f32 %0, %1" : "=v"(r) : "v"(f)); return r; }
__device__ __forceinline__ float sin2pi(float f){ float r; asm("v_sin_f32 %0, %1" : "=v"(r) : "v"(f)); return r; }

__device__ __forceinline__ short bf16_of(float f){
    union { __hip_bfloat16 h; short s; } u;
    u.h = __float2bfloat16(f);
    return u.s;
}

// ---- prep: fp32 coeffs -> bf16 fragment-ordered weights in d_ws (once per launch) ----
// Fragment layout (identical to the old in-block staging): [ks][nt][lane] -> short8
// k = br*384 + i*128 + g ; W[o,k] = coeffs[br, o, i, g]
extern "C" __global__ void prep_weights(const float* __restrict__ coeffs,
                                        short8* __restrict__ wfrag)
{
    const int fl = blockIdx.x * 256 + threadIdx.x;
    if (fl >= NFRAG) return;
    const int ks = fl >> 8;
    const int nt = (fl >> 6) & 3;
    const int ln = fl & 63;
    const int o  = nt*16 + (ln & 15);   // B-frag: col = lane & 15
    const int kg = ln >> 4;             // k sub-band = 4*(lane>>4)
    union { short8 v; short s[8]; } fr;
    #pragma unroll
    for (int h = 0; h < 2; ++h) {
        const int kb  = ks*32 + h*16;
        const int br  = (kb >= 384) ? 1 : 0;
        const int rem = kb - br*384;
        const int ii  = rem >> 7;
        const int g0  = (rem & 127) + kg*4;
        const float* wp = coeffs + (((br*ODIM + o)*3 + ii) << 7) + g0;
        #pragma unroll
        for (int j = 0; j < 4; ++j) fr.s[h*4 + j] = bf16_of(wp[j]);
    }
    wfrag[fl] = fr.v;
}

// ---- main: coalesced d_ws->LDS copy, then the proven R3 main loop ----
extern "C" __global__ void __launch_bounds__(TPB, 4)
fourier_mfma(const float* __restrict__ x,
             const short8* __restrict__ wfrag,
             const float* __restrict__ bias,
             float* __restrict__ out)
{
    __shared__ short8 Wlds[NFRAG];   // 98304 B

    const int tid = threadIdx.x;

    // Linear coalesced copy: 6 x 16 B per thread (global_load_dwordx4 + ds_write_b128)
    #pragma unroll
    for (int c = 0; c < NFRAG/TPB; ++c)
        Wlds[c*TPB + tid] = wfrag[c*TPB + tid];

    const int lane = tid & 63;
    const int wid  = tid >> 6;
    const int mrow = lane & 15;     // A-frag row within 16-row tile
    const int kgrp = lane >> 4;     // k sub-band / D-row group
    const float h0f = (float)(4*kgrp + 1);   // lane's anchor harmonic per 16-block

    const int unit = blockIdx.x * 16 + wid;   // 4096 units = NROWS/64
    const int base = unit * 64;

    // Preload x (revolutions) for all 4 row-tiles before the barrier.
    f32x2 xr[2][3];
    #pragma unroll
    for (int rg = 0; rg < 2; ++rg) {
        const int rowA = base + (rg*2 + 0)*16 + mrow;
        const int rowB = base + (rg*2 + 1)*16 + mrow;
        #pragma unroll
        for (int i = 0; i < 3; ++i)
            xr[rg][i] = (f32x2){ x[rowA*3 + i] * INV2PI, x[rowB*3 + i] * INV2PI };
    }
    float bcol[4];
    #pragma unroll
    for (int nt = 0; nt < 4; ++nt) bcol[nt] = bias[nt*16 + mrow];

    __syncthreads();

    for (int rg = 0; rg < 2; ++rg) {
        f32x4 acc[2][4];
        #pragma unroll
        for (int rr = 0; rr < 2; ++rr)
            #pragma unroll
            for (int nt = 0; nt < 4; ++nt)
                acc[rr][nt] = (f32x4){0.f, 0.f, 0.f, 0.f};

        f32x2 cvp, svp, c16p, s16p, stc, sts;

        #pragma unroll
        for (int kk = 0; kk < 12; ++kk) {          // cos k-step; sin is kk+12
            // early-issue this step's 8 b-frags (latency hides under feature gen)
            short8 bfr[8];                          // [branch*4 + nt], static idx
            #pragma unroll
            for (int nt = 0; nt < 4; ++nt) {
                bfr[nt]     = Wlds[(kk*4 + nt)*64 + lane];
                bfr[4 + nt] = Wlds[((kk + 12)*4 + nt)*64 + lane];
            }

            if ((kk & 3) == 0) {                    // per-input-dim trig setup
                const int i = kk >> 2;
                const f32x2 a = xr[rg][i];
                cvp = (f32x2){ cos2pi(a.x), cos2pi(a.y) };   // rotate by 1*x
                svp = (f32x2){ sin2pi(a.x), sin2pi(a.y) };
                f32x2 t = (f32x2){ 16.f*a.x, 16.f*a.y };
                t.x -= floorf(t.x); t.y -= floorf(t.y);
                c16p = (f32x2){ cos2pi(t.x), cos2pi(t.y) };  // rotate by 16*x
                s16p = (f32x2){ sin2pi(t.x), sin2pi(t.y) };
                f32x2 u = (f32x2){ h0f*a.x, h0f*a.y };
                u.x -= floorf(u.x); u.y -= floorf(u.y);
                stc = (f32x2){ cos2pi(u.x), cos2pi(u.y) };   // state: harmonic 4*kgrp+1
                sts = (f32x2){ sin2pi(u.x), sin2pi(u.y) };
            }

            union { short8 v; short s[8]; } fc[2], fs[2];
            #pragma unroll
            for (int h = 0; h < 2; ++h) {
                f32x2 c = stc, s = sts;
                fc[0].s[h*4] = bf16_of(c.x); fc[1].s[h*4] = bf16_of(c.y);
                fs[0].s[h*4] = bf16_of(s.x); fs[1].s[h*4] = bf16_of(s.y);
                #pragma unroll
                for (int j = 1; j < 4; ++j) {
                    const f32x2 cn = c*cvp - s*svp;   // dual-FMA rotation
                    const f32x2 sn = s*cvp + c*svp;
                    c = cn; s = sn;
                    fc[0].s[h*4+j] = bf16_of(c.x); fc[1].s[h*4+j] = bf16_of(c.y);
                    fs[0].s[h*4+j] = bf16_of(s.x); fs[1].s[h*4+j] = bf16_of(s.y);
                }
                const f32x2 nc = stc*c16p - sts*s16p; // advance state by 16*x
                const f32x2 ns = sts*c16p + stc*s16p;
                stc = nc; sts = ns;
            }

            #pragma unroll
            for (int nt = 0; nt < 4; ++nt) {
                #pragma unroll
                for (int rr = 0; rr < 2; ++rr) {
                    acc[rr][nt] = __builtin_amdgcn_mfma_f32_16x16x32_bf16(fc[rr].v, bfr[nt],     acc[rr][nt], 0, 0, 0);
                    acc[rr][nt] = __builtin_amdgcn_mfma_f32_16x16x32_bf16(fs[rr].v, bfr[4 + nt], acc[rr][nt], 0, 0, 0);
                }
            }
        }

        // Epilogue. D layout: col = lane&15, row = 4*(lane>>4) + reg  [m89-verified]
        #pragma unroll
        for (int rr = 0; rr < 2; ++rr) {
            const int row0 = base + (rg*2 + rr)*16 + kgrp*4;
            #pragma unroll
            for (int nt = 0; nt < 4; ++nt) {
                #pragma unroll
                for (int q = 0; q < 4; ++q) {
                    out[(row0 + q)*ODIM + nt*16 + mrow] = acc[rr][nt][q] + bcol[nt];
                }
            }
        }
    }
}

extern "C" void kernel_launch(void* const* d_in, const int* in_sizes, int n_in,
                              void* d_out, int out_size, void* d_ws, size_t ws_size,
                              hipStream_t stream) {
    const float* x      = (const float*)d_in[0];
    const float* coeffs = (const float*)d_in[1];
    const float* bias   = (const float*)d_in[2];
    float* out = (float*)d_out;
    short8* wfrag = (short8*)d_ws;    // 98304 B of workspace
    (void)in_sizes; (void)n_in; (void)out_size; (void)ws_size;
    hipLaunchKernelGGL(prep_weights, dim3((NFRAG + 255)/256), dim3(256), 0, stream, coeffs, wfrag);
    hipLaunchKernelGGL(fourier_mfma, dim3(NBLOCKS), dim3(TPB), 0, stream, x, wfrag, bias, out);
}

// Round 10
// 42.290 us; speedup vs baseline: 1.2644x; 1.2644x over previous
//
#include <hip/hip_runtime.h>
#include <hip/hip_bf16.h>

typedef __attribute__((ext_vector_type(8))) short short8;
typedef __attribute__((ext_vector_type(4))) float f32x4;
typedef __attribute__((ext_vector_type(2))) float f32x2;

#define NROWS   262144
#define ODIM    64
#define NBLOCKS 256
#define TPB     1024          // 16 waves; 98 KB LDS -> 1 block/CU -> 4 waves/SIMD
#define INV2PI  0.15915494309189535f

__device__ __forceinline__ float cos2pi(float f){ float r; asm("v_cos_f32 %0, %1" : "=v"(r) : "v"(f)); return r; }
__device__ __forceinline__ float sin2pi(float f){ float r; asm("v_sin_f32 %0, %1" : "=v"(r) : "v"(f)); return r; }

__device__ __forceinline__ short bf16_of(float f){
    union { __hip_bfloat16 h; short s; } u;
    u.h = __float2bfloat16(f);
    return u.s;
}

// out[b,o] = sum_k F[b,k] W[o,k]; k = br*384 + i*128 + g; harmonic = g+1
// cos k-step kk (0..11) pairs with sin k-step kk+12 (identical harmonics).
extern "C" __global__ void __launch_bounds__(TPB, 4)
fourier_mfma(const float* __restrict__ x,
             const float* __restrict__ coeffs,
             const float* __restrict__ bias,
             float* __restrict__ out)
{
    // Fragment-ordered bf16 weights: [ks][nt][lane] -> 8 bf16 (one ds_read_b128)
    __shared__ short8 Wlds[24 * 4 * 64];   // 98304 B

    const int tid = threadIdx.x;

    // ---- one-time weight staging: fp32 global -> bf16 fragments in LDS ----
    for (int fl = tid; fl < 24*4*64; fl += TPB) {
        const int ks = fl >> 8;
        const int nt = (fl >> 6) & 3;
        const int ln = fl & 63;
        const int o  = nt*16 + (ln & 15);   // B-frag: col = lane & 15
        const int kg = ln >> 4;             // k sub-band = 4*(lane>>4)
        union { short8 v; short s[8]; } fr;
        #pragma unroll
        for (int h = 0; h < 2; ++h) {
            const int kb  = ks*32 + h*16;
            const int br  = (kb >= 384) ? 1 : 0;
            const int rem = kb - br*384;
            const int ii  = rem >> 7;
            const int g0  = (rem & 127) + kg*4;
            const float* wp = coeffs + (((br*ODIM + o)*3 + ii) << 7) + g0;
            #pragma unroll
            for (int j = 0; j < 4; ++j) fr.s[h*4 + j] = bf16_of(wp[j]);
        }
        Wlds[fl] = fr.v;
    }
    __syncthreads();

    const int lane = tid & 63;
    const int wid  = tid >> 6;

    // ---- convoy breaker: one-time per-wave phase offset (persists: no more barriers).
    // (wid*5)&15 >> 2 gives each wave sharing a SIMD a distinct value in {0,1,2,3}
    // under both blocked (wid>>2) and round-robin (wid&3) wave->SIMD mappings.
    {
        const int ph = ((wid * 5) & 15) >> 2;
        if      (ph == 1) __builtin_amdgcn_s_sleep(11);   // ~700 cyc
        else if (ph == 2) __builtin_amdgcn_s_sleep(22);   // ~1400 cyc
        else if (ph == 3) __builtin_amdgcn_s_sleep(33);   // ~2100 cyc
    }

    const int mrow = lane & 15;     // A-frag row within 16-row tile
    const int kgrp = lane >> 4;     // k sub-band / D-row group
    const float hs = (float)(4*kgrp + 1);   // lane's starting harmonic per 16-block

    float bcol[4];
    #pragma unroll
    for (int nt = 0; nt < 4; ++nt) bcol[nt] = bias[nt*16 + mrow];

    const int unit = blockIdx.x * 16 + wid;   // 256*16 = 4096 units = NROWS/64
    const int base = unit * 64;

    // Two sequential 32-row passes; each pass handles a packed row-pair (rr=0,1).
    for (int rg = 0; rg < 2; ++rg) {
        const int rowA = base + (rg*2 + 0)*16 + mrow;
        const int rowB = base + (rg*2 + 1)*16 + mrow;

        // Preload x (revolutions) for both rows, all 3 input dims.
        f32x2 xr[3];
        #pragma unroll
        for (int i = 0; i < 3; ++i)
            xr[i] = (f32x2){ x[rowA*3 + i] * INV2PI, x[rowB*3 + i] * INV2PI };

        f32x4 acc[2][4];
        #pragma unroll
        for (int rr = 0; rr < 2; ++rr)
            #pragma unroll
            for (int nt = 0; nt < 4; ++nt)
                acc[rr][nt] = (f32x4){0.f, 0.f, 0.f, 0.f};

        f32x2 cvp, svp, c16p, s16p, stc, sts;

        #pragma unroll
        for (int kk = 0; kk < 12; ++kk) {          // cos k-step; sin is kk+12
            // -- early-issue this step's 8 b-frags (latency hides under feature gen)
            short8 bfr[8];                          // [branch*4 + nt], all static idx
            #pragma unroll
            for (int nt = 0; nt < 4; ++nt) {
                bfr[nt]     = Wlds[(kk*4 + nt)*64 + lane];
                bfr[4 + nt] = Wlds[((kk + 12)*4 + nt)*64 + lane];
            }

            if ((kk & 3) == 0) {                    // per-input-dim trig setup
                const int i = kk >> 2;
                const f32x2 a = xr[i];
                cvp = (f32x2){ cos2pi(a.x), cos2pi(a.y) };   // rotate by 1*x
                svp = (f32x2){ sin2pi(a.x), sin2pi(a.y) };
                f32x2 t = (f32x2){ 16.f*a.x, 16.f*a.y };
                t.x -= floorf(t.x); t.y -= floorf(t.y);
                c16p = (f32x2){ cos2pi(t.x), cos2pi(t.y) };  // rotate by 16*x
                s16p = (f32x2){ sin2pi(t.x), sin2pi(t.y) };
                f32x2 u = (f32x2){ hs*a.x, hs*a.y };
                u.x -= floorf(u.x); u.y -= floorf(u.y);
                stc = (f32x2){ cos2pi(u.x), cos2pi(u.y) };   // state: harmonic 4*kgrp+1
                sts = (f32x2){ sin2pi(u.x), sin2pi(u.y) };
            }

            union { short8 v; short s[8]; } fc[2], fs[2];
            #pragma unroll
            for (int h = 0; h < 2; ++h) {
                f32x2 c = stc, s = sts;
                fc[0].s[h*4] = bf16_of(c.x); fc[1].s[h*4] = bf16_of(c.y);
                fs[0].s[h*4] = bf16_of(s.x); fs[1].s[h*4] = bf16_of(s.y);
                #pragma unroll
                for (int j = 1; j < 4; ++j) {
                    const f32x2 cn = c*cvp - s*svp;   // dual rotation
                    const f32x2 sn = s*cvp + c*svp;
                    c = cn; s = sn;
                    fc[0].s[h*4+j] = bf16_of(c.x); fc[1].s[h*4+j] = bf16_of(c.y);
                    fs[0].s[h*4+j] = bf16_of(s.x); fs[1].s[h*4+j] = bf16_of(s.y);
                }
                const f32x2 nc = stc*c16p - sts*s16p; // advance state by 16*x
                const f32x2 ns = sts*c16p + stc*s16p;
                stc = nc; sts = ns;
            }

            #pragma unroll
            for (int nt = 0; nt < 4; ++nt) {
                #pragma unroll
                for (int rr = 0; rr < 2; ++rr) {
                    acc[rr][nt] = __builtin_amdgcn_mfma_f32_16x16x32_bf16(fc[rr].v, bfr[nt],     acc[rr][nt], 0, 0, 0);
                    acc[rr][nt] = __builtin_amdgcn_mfma_f32_16x16x32_bf16(fs[rr].v, bfr[4 + nt], acc[rr][nt], 0, 0, 0);
                }
            }
        }

        // Epilogue. D layout: col = lane&15, row = 4*(lane>>4) + reg  [m89-verified]
        #pragma unroll
        for (int rr = 0; rr < 2; ++rr) {
            const int row0 = base + (rg*2 + rr)*16 + kgrp*4;
            #pragma unroll
            for (int nt = 0; nt < 4; ++nt) {
                #pragma unroll
                for (int q = 0; q < 4; ++q) {
                    out[(row0 + q)*ODIM + nt*16 + mrow] = acc[rr][nt][q] + bcol[nt];
                }
            }
        }
    }
}

extern "C" void kernel_launch(void* const* d_in, const int* in_sizes, int n_in,
                              void* d_out, int out_size, void* d_ws, size_t ws_size,
                              hipStream_t stream) {
    const float* x      = (const float*)d_in[0];
    const float* coeffs = (const float*)d_in[1];
    const float* bias   = (const float*)d_in[2];
    float* out = (float*)d_out;
    (void)in_sizes; (void)n_in; (void)out_size; (void)d_ws; (void)ws_size;
    hipLaunchKernelGGL(fourier_mfma, dim3(NBLOCKS), dim3(TPB), 0, stream, x, coeffs, bias, out);
}

// Round 11
// 41.527 us; speedup vs baseline: 1.2876x; 1.0184x over previous
//
#include <hip/hip_runtime.h>
#include <hip/hip_bf16.h>

typedef __attribute__((ext_vector_type(8))) short short8;
typedef __attribute__((ext_vector_type(4))) float f32x4;
typedef __attribute__((ext_vector_type(2))) float f32x2;

#define NROWS   262144
#define ODIM    64
#define NBLOCKS 256
#define TPB     1024          // 16 waves; 98 KB LDS -> 1 block/CU -> 4 waves/SIMD
#define INV2PI  0.15915494309189535f

__device__ __forceinline__ float cos2pi(float f){ float r; asm("v_cos_f32 %0, %1" : "=v"(r) : "v"(f)); return r; }
__device__ __forceinline__ float sin2pi(float f){ float r; asm("v_sin_f32 %0, %1" : "=v"(r) : "v"(f)); return r; }

__device__ __forceinline__ short bf16_of(float f){
    union { __hip_bfloat16 h; short s; } u;
    u.h = __float2bfloat16(f);
    return u.s;
}

// out[b,o] = sum_k F[b,k] W[o,k]; k = br*384 + i*128 + g; harmonic = g+1
// cos k-step kk (0..11) pairs with sin k-step kk+12 (identical harmonics).
// R11: kk is a REAL loop (no unroll) — total code ~5 KB to fit the 32 KB I$.
extern "C" __global__ void __launch_bounds__(TPB, 4)
fourier_mfma(const float* __restrict__ x,
             const float* __restrict__ coeffs,
             const float* __restrict__ bias,
             float* __restrict__ out)
{
    // Fragment-ordered bf16 weights: [ks][nt][lane] -> 8 bf16 (one ds_read_b128)
    __shared__ short8 Wlds[24 * 4 * 64];   // 98304 B

    const int tid = threadIdx.x;

    // ---- one-time weight staging: fp32 global -> bf16 fragments in LDS ----
    for (int fl = tid; fl < 24*4*64; fl += TPB) {
        const int ks = fl >> 8;
        const int nt = (fl >> 6) & 3;
        const int ln = fl & 63;
        const int o  = nt*16 + (ln & 15);   // B-frag: col = lane & 15
        const int kg = ln >> 4;             // k sub-band = 4*(lane>>4)
        union { short8 v; short s[8]; } fr;
        #pragma unroll
        for (int h = 0; h < 2; ++h) {
            const int kb  = ks*32 + h*16;
            const int br  = (kb >= 384) ? 1 : 0;
            const int rem = kb - br*384;
            const int ii  = rem >> 7;
            const int g0  = (rem & 127) + kg*4;
            const float* wp = coeffs + (((br*ODIM + o)*3 + ii) << 7) + g0;
            #pragma unroll
            for (int j = 0; j < 4; ++j) fr.s[h*4 + j] = bf16_of(wp[j]);
        }
        Wlds[fl] = fr.v;
    }
    __syncthreads();

    const int lane = tid & 63;
    const int wid  = tid >> 6;
    const int mrow = lane & 15;     // A-frag row within 16-row tile
    const int kgrp = lane >> 4;     // k sub-band / D-row group
    const float hs = (float)(4*kgrp + 1);   // lane's starting harmonic per 16-block

    float bcol[4];
    #pragma unroll
    for (int nt = 0; nt < 4; ++nt) bcol[nt] = bias[nt*16 + mrow];

    const int unit = blockIdx.x * 16 + wid;   // 256*16 = 4096 units = NROWS/64
    const int base = unit * 64;

    // Two sequential 32-row passes; each pass handles a packed row-pair (rr=0,1).
    #pragma unroll 1
    for (int rg = 0; rg < 2; ++rg) {
        const int rowA = base + (rg*2 + 0)*16 + mrow;
        const int rowB = base + (rg*2 + 1)*16 + mrow;

        // Preload x (revolutions) for both rows, all 3 input dims.
        f32x2 xr[3];
        #pragma unroll
        for (int i = 0; i < 3; ++i)
            xr[i] = (f32x2){ x[rowA*3 + i] * INV2PI, x[rowB*3 + i] * INV2PI };

        f32x4 acc[2][4];
        #pragma unroll
        for (int rr = 0; rr < 2; ++rr)
            #pragma unroll
            for (int nt = 0; nt < 4; ++nt)
                acc[rr][nt] = (f32x4){0.f, 0.f, 0.f, 0.f};

        f32x2 cvp, svp, c16p, s16p, stc, sts;

        #pragma unroll 1
        for (int kk = 0; kk < 12; ++kk) {          // cos k-step; sin is kk+12
            // early-issue this step's 8 b-frags (latency hides under feature gen).
            // dynamic base + immediate offsets -> 8 ds_read_b128 off one address.
            short8 bfr[8];                          // [branch*4 + nt], static idx
            #pragma unroll
            for (int nt = 0; nt < 4; ++nt) {
                bfr[nt]     = Wlds[(kk*4 + nt)*64 + lane];
                bfr[4 + nt] = Wlds[((kk + 12)*4 + nt)*64 + lane];
            }

            if ((kk & 3) == 0) {                    // uniform branch, every 4th iter
                const int i = kk >> 2;
                const f32x2 a = xr[i];
                cvp = (f32x2){ cos2pi(a.x), cos2pi(a.y) };   // rotate by 1*x
                svp = (f32x2){ sin2pi(a.x), sin2pi(a.y) };
                f32x2 t = (f32x2){ 16.f*a.x, 16.f*a.y };
                t.x -= floorf(t.x); t.y -= floorf(t.y);
                c16p = (f32x2){ cos2pi(t.x), cos2pi(t.y) };  // rotate by 16*x
                s16p = (f32x2){ sin2pi(t.x), sin2pi(t.y) };
                f32x2 u = (f32x2){ hs*a.x, hs*a.y };
                u.x -= floorf(u.x); u.y -= floorf(u.y);
                stc = (f32x2){ cos2pi(u.x), cos2pi(u.y) };   // state: harmonic 4*kgrp+1
                sts = (f32x2){ sin2pi(u.x), sin2pi(u.y) };
            }

            union { short8 v; short s[8]; } fc[2], fs[2];
            #pragma unroll
            for (int h = 0; h < 2; ++h) {
                f32x2 c = stc, s = sts;
                fc[0].s[h*4] = bf16_of(c.x); fc[1].s[h*4] = bf16_of(c.y);
                fs[0].s[h*4] = bf16_of(s.x); fs[1].s[h*4] = bf16_of(s.y);
                #pragma unroll
                for (int j = 1; j < 4; ++j) {
                    const f32x2 cn = c*cvp - s*svp;   // dual rotation
                    const f32x2 sn = s*cvp + c*svp;
                    c = cn; s = sn;
                    fc[0].s[h*4+j] = bf16_of(c.x); fc[1].s[h*4+j] = bf16_of(c.y);
                    fs[0].s[h*4+j] = bf16_of(s.x); fs[1].s[h*4+j] = bf16_of(s.y);
                }
                const f32x2 nc = stc*c16p - sts*s16p; // advance state by 16*x
                const f32x2 ns = sts*c16p + stc*s16p;
                stc = nc; sts = ns;
            }

            #pragma unroll
            for (int nt = 0; nt < 4; ++nt) {
                #pragma unroll
                for (int rr = 0; rr < 2; ++rr) {
                    acc[rr][nt] = __builtin_amdgcn_mfma_f32_16x16x32_bf16(fc[rr].v, bfr[nt],     acc[rr][nt], 0, 0, 0);
                    acc[rr][nt] = __builtin_amdgcn_mfma_f32_16x16x32_bf16(fs[rr].v, bfr[4 + nt], acc[rr][nt], 0, 0, 0);
                }
            }
        }

        // Epilogue. D layout: col = lane&15, row = 4*(lane>>4) + reg  [m89-verified]
        #pragma unroll
        for (int rr = 0; rr < 2; ++rr) {
            const int row0 = base + (rg*2 + rr)*16 + kgrp*4;
            #pragma unroll
            for (int nt = 0; nt < 4; ++nt) {
                #pragma unroll
                for (int q = 0; q < 4; ++q) {
                    out[(row0 + q)*ODIM + nt*16 + mrow] = acc[rr][nt][q] + bcol[nt];
                }
            }
        }
    }
}

extern "C" void kernel_launch(void* const* d_in, const int* in_sizes, int n_in,
                              void* d_out, int out_size, void* d_ws, size_t ws_size,
                              hipStream_t stream) {
    const float* x      = (const float*)d_in[0];
    const float* coeffs = (const float*)d_in[1];
    const float* bias   = (const float*)d_in[2];
    float* out = (float*)d_out;
    (void)in_sizes; (void)n_in; (void)out_size; (void)d_ws; (void)ws_size;
    hipLaunchKernelGGL(fourier_mfma, dim3(NBLOCKS), dim3(TPB), 0, stream, x, coeffs, bias, out);
}